// Round 6
// baseline (185.671 us; speedup 1.0000x reference)
//
#include <hip/hip_runtime.h>
#include <hip/hip_bf16.h>

// Problem constants
#define HW 16384        // 128*128
#define IMGW 128
#define Bsz 2
#define Cc 192          // channels
#define NH 4
#define CH 48
static const size_t CP = (size_t)Cc * HW;   // one batch's 192-channel block

typedef __attribute__((ext_vector_type(4))) float f32x4;
typedef __attribute__((ext_vector_type(8))) short short8;
typedef __attribute__((ext_vector_type(8))) unsigned short bf16x8;
typedef __attribute__((ext_vector_type(4))) unsigned short bf16x4;

__device__ __forceinline__ unsigned short f2bf(float f) {
  __hip_bfloat16 h = __float2bfloat16(f);
  return *reinterpret_cast<unsigned short*>(&h);
}
__device__ __forceinline__ float bf2f(unsigned short u) {
  union { unsigned int i; float f; } v;
  v.i = (unsigned int)u << 16;
  return v.f;
}

// ---------------------------------------------------------------------------
// weights fp32 -> bf16 (both weight mats in one launch)
// ---------------------------------------------------------------------------
#define NWQKV (576 * 192)
#define NWKV  (384 * 192)
__global__ __launch_bounds__(256) void cast_weights_kernel(
    const float* __restrict__ qkv_w, const float* __restrict__ kv_w,
    unsigned short* __restrict__ wqkv, unsigned short* __restrict__ wkv) {
  int i = blockIdx.x * 256 + threadIdx.x;
  if (i < NWQKV) wqkv[i] = f2bf(qkv_w[i]);
  else if (i < NWQKV + NWKV) wkv[i - NWQKV] = f2bf(kv_w[i - NWQKV]);
}

// ---------------------------------------------------------------------------
// conv1x1 bf16 MFMA GEMM with fused transpose staging.
// D[m=hw][n=o] = sum_c SRC[c][hw] * W[o][c]
// INKIND 1: src fp32 [c][hw];  INKIND 2: src bf16 [c][hw].
// Tile 128(hw) x 64(o), K=192 in 3 steps of 64. 4 waves (2m x 2n).
// A staged transposed in LDS: (c,c+1) bf16 pair packed to u32 at [hw][c].
// ---------------------------------------------------------------------------
#define BMH 128
#define BNO 64
#define BKC 64
#define PADK 72   // shorts; row stride 144B; PADK/2=36 u32

template <int INKIND, int OUTBF16>
__global__ __launch_bounds__(256) void conv_mfma_kernel(
    const void* __restrict__ src, size_t src_bstride,     // elements
    const unsigned short* __restrict__ wb, size_t wstride, // per-batch (0 = shared)
    void* __restrict__ outv, int Cout) {
  __shared__ __align__(16) short As[BMH * PADK];
  __shared__ __align__(16) short Bs[BNO * PADK];
  unsigned int* As32 = (unsigned int*)As;
  const int b = blockIdx.z;
  const int hw0 = blockIdx.x * BMH;
  const int o0 = blockIdx.y * BNO;
  const int tid = threadIdx.x;
  const int lane = tid & 63, wid = tid >> 6;
  const int wm = wid & 1, wn = wid >> 1;
  const unsigned short* wbb = wb + (size_t)b * wstride + (size_t)o0 * Cc;
  const int cp = tid & 31;        // c-pair within k-slice
  const int hq0 = tid >> 5;       // 0..7
  f32x4 acc[4][2] = {};
  for (int k0 = 0; k0 < Cc; k0 += BKC) {
    // ---- A staging: transpose [c][hw] -> LDS [hw][c] via packed u32 ----
    if (INKIND == 1) {
      const float* r0 = (const float*)src + (size_t)b * src_bstride +
                        (size_t)(k0 + 2 * cp) * HW + hw0;
      const float* r1 = r0 + HW;
      #pragma unroll
      for (int s = 0; s < 4; ++s) {
        int hw = (hq0 + 8 * s) * 4;
        f32x4 v0 = *(const f32x4*)(r0 + hw);
        f32x4 v1 = *(const f32x4*)(r1 + hw);
        #pragma unroll
        for (int i = 0; i < 4; ++i)
          As32[(hw + i) * (PADK / 2) + cp] =
              (unsigned int)f2bf(v0[i]) | ((unsigned int)f2bf(v1[i]) << 16);
      }
    } else {
      const unsigned short* r0 = (const unsigned short*)src +
                                 (size_t)b * src_bstride +
                                 (size_t)(k0 + 2 * cp) * HW + hw0;
      const unsigned short* r1 = r0 + HW;
      #pragma unroll
      for (int s = 0; s < 2; ++s) {
        int hw = (hq0 + 8 * s) * 8;
        bf16x8 v0 = *(const bf16x8*)(r0 + hw);
        bf16x8 v1 = *(const bf16x8*)(r1 + hw);
        #pragma unroll
        for (int i = 0; i < 8; ++i)
          As32[(hw + i) * (PADK / 2) + cp] =
              (unsigned int)v0[i] | ((unsigned int)v1[i] << 16);
      }
    }
    // ---- B staging: [o][c] rows, contiguous ----
    #pragma unroll
    for (int p = 0; p < 2; ++p) {
      int i = tid + p * 256;
      int row = i >> 3, cc = i & 7;
      *(short8*)&Bs[row * PADK + cc * 8] =
          *(const short8*)(wbb + (size_t)row * Cc + k0 + cc * 8);
    }
    __syncthreads();
    #pragma unroll
    for (int ks = 0; ks < 2; ++ks) {
      short8 bfrag[2];
      #pragma unroll
      for (int fn = 0; fn < 2; ++fn)
        bfrag[fn] = *(short8*)&Bs[(wn * 32 + fn * 16 + (lane & 15)) * PADK +
                                  ks * 32 + (lane >> 4) * 8];
      #pragma unroll
      for (int fm = 0; fm < 4; ++fm) {
        short8 afrag = *(short8*)&As[(wm * 64 + fm * 16 + (lane & 15)) * PADK +
                                     ks * 32 + (lane >> 4) * 8];
        #pragma unroll
        for (int fn = 0; fn < 2; ++fn)
          acc[fm][fn] = __builtin_amdgcn_mfma_f32_16x16x32_bf16(
              afrag, bfrag[fn], acc[fm][fn], 0, 0, 0);
      }
    }
    __syncthreads();
  }
  #pragma unroll
  for (int fm = 0; fm < 4; ++fm)
    #pragma unroll
    for (int fn = 0; fn < 2; ++fn) {
      int o = o0 + wn * 32 + fn * 16 + (lane & 15);
      int hw = hw0 + wm * 64 + fm * 16 + ((lane >> 4) << 2);
      if (OUTBF16) {
        bf16x4 u;
        #pragma unroll
        for (int r = 0; r < 4; ++r) u[r] = f2bf(acc[fm][fn][r]);
        *(bf16x4*)&((unsigned short*)outv)[((size_t)b * Cout + o) * HW + hw] = u;
      } else {
        *(f32x4*)&((float*)outv)[((size_t)b * Cout + o) * HW + hw] = acc[fm][fn];
      }
    }
}

// ---------------------------------------------------------------------------
// depthwise 3x3 SAME, bf16 in/out, fp32 accum. 8 px/thread.
// ---------------------------------------------------------------------------
__global__ __launch_bounds__(256) void dwconv_kernel(
    const unsigned short* __restrict__ in, const float* __restrict__ wgt,
    unsigned short* __restrict__ out, int Ctot) {
  const int b = blockIdx.z, ch = blockIdx.y;
  const int p0 = blockIdx.x * 2048 + threadIdx.x * 8;
  const int y = p0 >> 7, x0 = p0 & 127;
  const unsigned short* ip = in + ((size_t)b * Ctot + ch) * HW;
  const float* wp = wgt + ch * 9;
  float acc[8] = {};
  #pragma unroll
  for (int dy = -1; dy <= 1; ++dy) {
    int yy = y + dy;
    if (yy < 0 || yy > IMGW - 1) continue;
    const unsigned short* rp = ip + yy * IMGW;
    float r[10];
    bf16x8 mid = *(const bf16x8*)&rp[x0];
    #pragma unroll
    for (int e = 0; e < 8; ++e) r[e + 1] = bf2f(mid[e]);
    r[0] = (x0 > 0) ? bf2f(rp[x0 - 1]) : 0.f;
    r[9] = (x0 < 120) ? bf2f(rp[x0 + 8]) : 0.f;
    #pragma unroll
    for (int dx = 0; dx < 3; ++dx) {
      float wv = wp[(dy + 1) * 3 + dx];
      #pragma unroll
      for (int e = 0; e < 8; ++e) acc[e] += wv * r[e + dx];
    }
  }
  bf16x8 u;
  #pragma unroll
  for (int e = 0; e < 8; ++e) u[e] = f2bf(acc[e]);
  *(bf16x8*)&out[((size_t)b * Ctot + ch) * HW + p0] = u;
}

// ---------------------------------------------------------------------------
// L2 norms for Q, K2, K in one launch. kind = blockIdx.x / 384.
// inv[kind*384 + b*192 + r] = 1/max(||row||, 1e-12)
// ---------------------------------------------------------------------------
__global__ __launch_bounds__(256) void norm3_kernel(
    const unsigned short* __restrict__ qkvb,
    const unsigned short* __restrict__ kvb, float* __restrict__ inv) {
  const int kind = blockIdx.x / 384;
  const int row = blockIdx.x % 384;
  const int b = row / Cc, r = row % Cc;
  const unsigned short* p;
  if (kind == 0)      p = qkvb + (size_t)b * 3 * CP + (size_t)r * HW;
  else if (kind == 1) p = kvb + (size_t)b * 2 * CP + (size_t)r * HW;
  else                p = qkvb + (size_t)b * 3 * CP + CP + (size_t)r * HW;
  float s = 0.f;
  for (int i = threadIdx.x * 8; i < HW; i += 2048) {
    bf16x8 u = *(const bf16x8*)&p[i];
    #pragma unroll
    for (int j = 0; j < 8; ++j) {
      float v = bf2f(u[j]);
      s += v * v;
    }
  }
  #pragma unroll
  for (int off = 32; off; off >>= 1) s += __shfl_down(s, off);
  __shared__ float red[4];
  if ((threadIdx.x & 63) == 0) red[threadIdx.x >> 6] = s;
  __syncthreads();
  if (threadIdx.x == 0) {
    float t = red[0] + red[1] + red[2] + red[3];
    inv[blockIdx.x] = 1.f / fmaxf(sqrtf(t), 1e-12f);
  }
}

// ---------------------------------------------------------------------------
// Gram partials via MFMA, all 3 pairs in one launch (blockIdx.z = pair).
// grid (16 chunks, 8 bh, 3). chunk = 1024 n -> 8 iters of 128.
// spart[((pair*8+bh)*16 + chunk)*2304]
// ---------------------------------------------------------------------------
#define PK 136
#define NCHUNK 16
__global__ __launch_bounds__(256) void gram_mfma_kernel(
    const unsigned short* __restrict__ qkvb,
    const unsigned short* __restrict__ kvb, float* __restrict__ spart) {
  __shared__ __align__(16) char lds_raw[4 * 2304 * 4];
  short* Qs = (short*)lds_raw;
  short* Ks = Qs + 48 * PK;
  float* Rs = (float*)lds_raw;
  const int pair = blockIdx.z;
  const int bh = blockIdx.y, b = bh >> 2, hd = bh & 3;
  const int n0 = blockIdx.x * 1024;
  const int tid = threadIdx.x, lane = tid & 63, wid = tid >> 6;
  const unsigned short *ap, *bp;
  size_t as_, bs_;
  if (pair == 0)      { ap = qkvb;      as_ = 3 * CP; bp = kvb;       bs_ = 2 * CP; }
  else if (pair == 1) { ap = kvb + CP;  as_ = 2 * CP; bp = qkvb + CP; bs_ = 3 * CP; }
  else                { ap = kvb + CP;  as_ = 2 * CP; bp = kvb + CP;  bs_ = 2 * CP; }
  const unsigned short* qb = ap + (size_t)b * as_ + (size_t)(hd * CH) * HW + n0;
  const unsigned short* kb = bp + (size_t)b * bs_ + (size_t)(hd * CH) * HW + n0;
  f32x4 acc[3][3] = {};
  #pragma unroll 1
  for (int it = 0; it < 8; ++it) {
    #pragma unroll
    for (int p = 0; p < 3; ++p) {
      int c = tid + p * 256;
      int row = c >> 4, col = c & 15;
      *(short8*)&Qs[row * PK + col * 8] =
          *(const short8*)(qb + (size_t)row * HW + it * 128 + col * 8);
      *(short8*)&Ks[row * PK + col * 8] =
          *(const short8*)(kb + (size_t)row * HW + it * 128 + col * 8);
    }
    __syncthreads();
    short8 af[3], bfr[3];
    #pragma unroll
    for (int t = 0; t < 3; ++t) {
      af[t]  = *(short8*)&Qs[(t * 16 + (lane & 15)) * PK + wid * 32 + (lane >> 4) * 8];
      bfr[t] = *(short8*)&Ks[(t * 16 + (lane & 15)) * PK + wid * 32 + (lane >> 4) * 8];
    }
    #pragma unroll
    for (int mt = 0; mt < 3; ++mt)
      #pragma unroll
      for (int nt = 0; nt < 3; ++nt)
        acc[mt][nt] = __builtin_amdgcn_mfma_f32_16x16x32_bf16(
            af[mt], bfr[nt], acc[mt][nt], 0, 0, 0);
    __syncthreads();
  }
  #pragma unroll
  for (int mt = 0; mt < 3; ++mt)
    #pragma unroll
    for (int nt = 0; nt < 3; ++nt)
      #pragma unroll
      for (int r = 0; r < 4; ++r) {
        int i = mt * 16 + ((lane >> 4) << 2) + r;
        int j = nt * 16 + (lane & 15);
        Rs[wid * 2304 + i * 48 + j] = acc[mt][nt][r];
      }
  __syncthreads();
  float* sp = spart + ((size_t)(pair * 8 + bh) * NCHUNK + blockIdx.x) * 2304;
  for (int e = tid; e < 2304; e += 256)
    sp[e] = Rs[e] + Rs[2304 + e] + Rs[2 * 2304 + e] + Rs[3 * 2304 + e];
}

// ---------------------------------------------------------------------------
// Reduce 16 chunk-partials: G[(pair*8+bh)*2304 + e]
// ---------------------------------------------------------------------------
__global__ __launch_bounds__(256) void gram_reduce_kernel(
    const float* __restrict__ spart, float* __restrict__ G) {
  int idx = blockIdx.x * 256 + threadIdx.x;
  if (idx >= 3 * 8 * 2304) return;
  int pb = idx / 2304;
  int e = idx - pb * 2304;
  const float* sp = spart + (size_t)pb * NCHUNK * 2304 + e;
  float s = 0.f;
  #pragma unroll
  for (int c = 0; c < NCHUNK; ++c) s += sp[(size_t)c * 2304];
  G[idx] = s;
}

// ---------------------------------------------------------------------------
// Per-bh finalize + M projection. One block per bh (8 blocks).
// G: pair0=Q*K2^T, pair1=V2*K^T, pair2=V2*V2^T.
// Writes Mb[b][o][hd*48+j] = sum_i P[o][hd*48+i] * A2[i][j]  (bf16)
// ---------------------------------------------------------------------------
__global__ __launch_bounds__(256) void finalize_kernel(
    const float* __restrict__ G, const float* __restrict__ inv,
    const float* __restrict__ temp, const float* __restrict__ proj_w,
    unsigned short* __restrict__ Mb) {
  __shared__ float A1[2304], B1[2304], C1[2304];
  __shared__ unsigned short Pb[192 * 48];
  __shared__ float invq1[48];
  const int bh = blockIdx.x, b = bh >> 2, hd = bh & 3;
  const int tid = threadIdx.x;
  const float tp = temp[hd];
  const float* invQ  = inv;
  const float* invK2 = inv + 384;
  const float* invK  = inv + 768;
  // stage P column-slice as bf16
  for (int e = tid; e < 192 * 48; e += 256) {
    int o = e / 48, i = e - (e / 48) * 48;
    Pb[e] = f2bf(proj_w[(size_t)o * Cc + hd * 48 + i]);
  }
  // S1 scaled -> A1
  for (int e = tid; e < 2304; e += 256) {
    int i = e / 48, j = e - i * 48;
    A1[e] = G[(size_t)(0 * 8 + bh) * 2304 + e] *
            invQ[b * Cc + hd * CH + i] * invK2[b * Cc + hd * CH + j] * tp;
  }
  __syncthreads();
  if (tid < 48) {              // softmax rows of A1 in place
    float m = -1e30f;
    for (int j = 0; j < 48; ++j) m = fmaxf(m, A1[tid * 48 + j]);
    float sum = 0.f;
    for (int j = 0; j < 48; ++j) {
      float e2 = expf(A1[tid * 48 + j] - m);
      A1[tid * 48 + j] = e2;
      sum += e2;
    }
    float r = 1.f / sum;
    for (int j = 0; j < 48; ++j) A1[tid * 48 + j] *= r;
  }
  __syncthreads();
  // B1 = Gvv
  for (int e = tid; e < 2304; e += 256)
    B1[e] = G[(size_t)(2 * 8 + bh) * 2304 + e];
  __syncthreads();
  // C1 = A1 * Gvv
  for (int e = tid; e < 2304; e += 256) {
    int i = e / 48, j = e - i * 48;
    float s = 0.f;
    #pragma unroll 8
    for (int d = 0; d < 48; ++d) s += A1[i * 48 + d] * B1[d * 48 + j];
    C1[e] = s;
  }
  __syncthreads();
  if (tid < 48) {
    float s = 0.f;
    for (int j = 0; j < 48; ++j) s += C1[tid * 48 + j] * A1[tid * 48 + j];
    invq1[tid] = 1.f / fmaxf(sqrtf(fmaxf(s, 0.f)), 1e-12f);
  }
  __syncthreads();
  // B1 = Gvk
  for (int e = tid; e < 2304; e += 256)
    B1[e] = G[(size_t)(1 * 8 + bh) * 2304 + e];
  __syncthreads();
  // C1 = S2 = invq1 * (A1*Gvk) * invK * tp
  for (int e = tid; e < 2304; e += 256) {
    int i = e / 48, j = e - i * 48;
    float s = 0.f;
    #pragma unroll 8
    for (int d = 0; d < 48; ++d) s += A1[i * 48 + d] * B1[d * 48 + j];
    C1[e] = s * invq1[i] * invK[b * Cc + hd * CH + j] * tp;
  }
  __syncthreads();
  if (tid < 48) {              // softmax rows of C1 in place -> A2
    float m = -1e30f;
    for (int j = 0; j < 48; ++j) m = fmaxf(m, C1[tid * 48 + j]);
    float sum = 0.f;
    for (int j = 0; j < 48; ++j) {
      float e2 = expf(C1[tid * 48 + j] - m);
      C1[tid * 48 + j] = e2;
      sum += e2;
    }
    float r = 1.f / sum;
    for (int j = 0; j < 48; ++j) C1[tid * 48 + j] *= r;
  }
  __syncthreads();
  // M slice: Mb[b][o][hd*48+j]
  for (int e = tid; e < 192 * 48; e += 256) {
    int o = e / 48, j = e - (e / 48) * 48;
    float s = 0.f;
    #pragma unroll 8
    for (int i2 = 0; i2 < 48; ++i2) s += bf2f(Pb[o * 48 + i2]) * C1[i2 * 48 + j];
    Mb[((size_t)b * Cc + o) * Cc + hd * 48 + j] = f2bf(s);
  }
}

// ---------------------------------------------------------------------------
extern "C" void kernel_launch(void* const* d_in, const int* in_sizes, int n_in,
                              void* d_out, int out_size, void* d_ws, size_t ws_size,
                              hipStream_t stream) {
  const float* x      = (const float*)d_in[0];
  const float* y      = (const float*)d_in[1];
  const float* qkv_w  = (const float*)d_in[2];
  const float* dw_w   = (const float*)d_in[3];
  const float* kv_w   = (const float*)d_in[4];
  const float* proj_w = (const float*)d_in[5];
  const float* temp   = (const float*)d_in[6];
  float* out = (float*)d_out;
  float* ws  = (float*)d_ws;

  const size_t SF = (size_t)Bsz * CP;   // 6,291,456 elements
  unsigned short* qkvb   = (unsigned short*)ws;                 // 3SF shorts
  unsigned short* kvb    = (unsigned short*)(ws + 3 * SF / 2);  // 2SF shorts
  unsigned short* qkvpre = (unsigned short*)(ws + 5 * SF / 2);  // 3SF shorts -> ends 4SF
  float* inv   = ws + 4 * SF;                       // 1152
  float* spart = inv + 1152;                        // 3*8*16*2304 = 884,736
  float* G     = spart + (size_t)3 * 8 * NCHUNK * 2304;  // 55,296
  unsigned short* Mb   = (unsigned short*)(G + 3 * 8 * 2304);  // 73,728 shorts
  unsigned short* wqkv = Mb + (size_t)Bsz * Cc * Cc;
  unsigned short* wkv  = wqkv + NWQKV;

  dim3 blk(256);

  // 0. weight casts (one launch)
  cast_weights_kernel<<<dim3((NWQKV + NWKV + 255) / 256), blk, 0, stream>>>(
      qkv_w, kv_w, wqkv, wkv);

  // 1. qkv_pre = conv1x1(x, qkv_w)  [fp32 src, fused transpose]
  conv_mfma_kernel<1, 1><<<dim3(HW / BMH, 576 / BNO, Bsz), blk, 0, stream>>>(
      x, CP, wqkv, 0, qkvpre, 3 * Cc);
  // 2. qkv = dwconv3x3(qkv_pre)
  dwconv_kernel<<<dim3(HW / 2048, 3 * Cc, Bsz), blk, 0, stream>>>(
      qkvpre, dw_w, qkvb, 3 * Cc);
  // 3. kv = conv1x1(y, kv_w)
  conv_mfma_kernel<1, 1><<<dim3(HW / BMH, 384 / BNO, Bsz), blk, 0, stream>>>(
      y, CP, wkv, 0, kvb, 2 * Cc);

  // 4. norms (Q, K2, K) in one launch
  norm3_kernel<<<dim3(3 * 384), blk, 0, stream>>>(qkvb, kvb, inv);

  // 5. Gram partials, 3 pairs in one launch
  gram_mfma_kernel<<<dim3(NCHUNK, 8, 3), blk, 0, stream>>>(qkvb, kvb, spart);

  // 6. reduce + finalize (softmax chain + M = P * A2_blockdiag)
  gram_reduce_kernel<<<dim3(216), blk, 0, stream>>>(spart, G);
  finalize_kernel<<<dim3(8), blk, 0, stream>>>(G, inv, temp, proj_w, Mb);

  // 7. out = M * V   (V = qkv slice 2, bf16 [c][hw], fused transpose)
  conv_mfma_kernel<2, 0><<<dim3(HW / BMH, Cc / BNO, Bsz), blk, 0, stream>>>(
      qkvb + 2 * CP, 3 * CP, Mb, (size_t)Cc * Cc, out, Cc);
}

// Round 8
// 132.252 us; speedup vs baseline: 1.4039x; 1.4039x over previous
//
#include <hip/hip_runtime.h>
#include <hip/hip_bf16.h>

// Problem constants
#define HW 16384        // 128*128
#define IMGW 128
#define Bsz 2
#define Cc 192          // channels
#define NH 4
#define CH 48
static const size_t CP = (size_t)Cc * HW;   // one batch's 192-channel block

typedef __attribute__((ext_vector_type(4))) float f32x4;
typedef __attribute__((ext_vector_type(8))) short short8;
typedef __attribute__((ext_vector_type(8))) unsigned short bf16x8;
typedef __attribute__((ext_vector_type(4))) unsigned short bf16x4;

__device__ __forceinline__ unsigned short f2bf(float f) {
  __hip_bfloat16 h = __float2bfloat16(f);
  return *reinterpret_cast<unsigned short*>(&h);
}
__device__ __forceinline__ float bf2f(unsigned short u) {
  union { unsigned int i; float f; } v;
  v.i = (unsigned int)u << 16;
  return v.f;
}

// ---------------------------------------------------------------------------
// weights fp32 -> bf16 (both weight mats, one launch)
// ---------------------------------------------------------------------------
#define NWQKV (576 * 192)
#define NWKV  (384 * 192)
__global__ __launch_bounds__(256) void cast_weights_kernel(
    const float* __restrict__ qkv_w, const float* __restrict__ kv_w,
    unsigned short* __restrict__ wqkv, unsigned short* __restrict__ wkv) {
  int i = blockIdx.x * 256 + threadIdx.x;
  if (i < NWQKV) wqkv[i] = f2bf(qkv_w[i]);
  else if (i < NWQKV + NWKV) wkv[i - NWQKV] = f2bf(kv_w[i - NWQKV]);
}

// ---------------------------------------------------------------------------
// Cast fp32 [b][192][HW] -> bf16 transposed [b][HW][192], x and y in one
// launch. grid (HW/256, 24, 4): z&1 = batch, z>>1 = which tensor.
// ---------------------------------------------------------------------------
__global__ __launch_bounds__(256) void cast_xy_kernel(
    const float* __restrict__ x, const float* __restrict__ y,
    unsigned short* __restrict__ xt, unsigned short* __restrict__ yt) {
  const int z = blockIdx.z;
  const int b = z & 1;
  const float* in = (z >> 1) ? y : x;
  unsigned short* outt = (z >> 1) ? yt : xt;
  const int c0 = blockIdx.y * 8;
  const int hw = blockIdx.x * 256 + threadIdx.x;
  const float* ib = in + (size_t)b * CP;
  bf16x8 u;
  #pragma unroll
  for (int j = 0; j < 8; ++j)
    u[j] = f2bf(ib[(size_t)(c0 + j) * HW + hw]);
  *(bf16x8*)&outt[(size_t)b * CP + (size_t)hw * Cc + c0] = u;
}

// ---------------------------------------------------------------------------
// conv1x1 bf16 MFMA GEMM (round-5 proven form).
// D[m=hw][n=o] = sum_c Xt[hw][c] * W[o][c]; tile 128x64, 4 waves (2m x 2n).
// ---------------------------------------------------------------------------
#define BMH 128
#define BNO 64
#define BKC 64
#define PADK 72

template <int OUTBF16>
__global__ __launch_bounds__(256) void conv_mfma_kernel(
    const unsigned short* __restrict__ xt,   // [b][HW][192] bf16
    const unsigned short* __restrict__ wb,   // [Cout][192] bf16 (+ b*wstride)
    void* __restrict__ outv, int Cout, size_t wstride) {
  __shared__ __align__(16) short As[BMH * PADK];
  __shared__ __align__(16) short Bs[BNO * PADK];
  const int b = blockIdx.z;
  const int hw0 = blockIdx.x * BMH;
  const int o0 = blockIdx.y * BNO;
  const int tid = threadIdx.x;
  const int lane = tid & 63, wid = tid >> 6;
  const int wm = wid & 1, wn = wid >> 1;
  const unsigned short* xtb = xt + (size_t)b * CP + (size_t)hw0 * Cc;
  const unsigned short* wbb = wb + (size_t)b * wstride + (size_t)o0 * Cc;
  f32x4 acc[4][2] = {};
  for (int k0 = 0; k0 < Cc; k0 += BKC) {
    #pragma unroll
    for (int p = 0; p < 4; ++p) {
      int i = tid + p * 256;
      int row = i >> 3, cc = i & 7;
      *(short8*)&As[row * PADK + cc * 8] =
          *(const short8*)(xtb + (size_t)row * Cc + k0 + cc * 8);
    }
    #pragma unroll
    for (int p = 0; p < 2; ++p) {
      int i = tid + p * 256;
      int row = i >> 3, cc = i & 7;
      *(short8*)&Bs[row * PADK + cc * 8] =
          *(const short8*)(wbb + (size_t)row * Cc + k0 + cc * 8);
    }
    __syncthreads();
    #pragma unroll
    for (int ks = 0; ks < 2; ++ks) {
      short8 bfrag[2];
      #pragma unroll
      for (int fn = 0; fn < 2; ++fn)
        bfrag[fn] = *(short8*)&Bs[(wn * 32 + fn * 16 + (lane & 15)) * PADK +
                                  ks * 32 + (lane >> 4) * 8];
      #pragma unroll
      for (int fm = 0; fm < 4; ++fm) {
        short8 afrag = *(short8*)&As[(wm * 64 + fm * 16 + (lane & 15)) * PADK +
                                     ks * 32 + (lane >> 4) * 8];
        #pragma unroll
        for (int fn = 0; fn < 2; ++fn)
          acc[fm][fn] = __builtin_amdgcn_mfma_f32_16x16x32_bf16(
              afrag, bfrag[fn], acc[fm][fn], 0, 0, 0);
      }
    }
    __syncthreads();
  }
  #pragma unroll
  for (int fm = 0; fm < 4; ++fm)
    #pragma unroll
    for (int fn = 0; fn < 2; ++fn) {
      int o = o0 + wn * 32 + fn * 16 + (lane & 15);
      int hw = hw0 + wm * 64 + fm * 16 + ((lane >> 4) << 2);
      if (OUTBF16) {
        bf16x4 u;
        #pragma unroll
        for (int r = 0; r < 4; ++r) u[r] = f2bf(acc[fm][fn][r]);
        *(bf16x4*)&((unsigned short*)outv)[((size_t)b * Cout + o) * HW + hw] = u;
      } else {
        *(f32x4*)&((float*)outv)[((size_t)b * Cout + o) * HW + hw] = acc[fm][fn];
      }
    }
}

// ---------------------------------------------------------------------------
// depthwise 3x3 SAME, bf16 in/out, fp32 accum. 8 px/thread.
// ---------------------------------------------------------------------------
__global__ __launch_bounds__(256) void dwconv_kernel(
    const unsigned short* __restrict__ in, const float* __restrict__ wgt,
    unsigned short* __restrict__ out, int Ctot) {
  const int b = blockIdx.z, ch = blockIdx.y;
  const int p0 = blockIdx.x * 2048 + threadIdx.x * 8;
  const int y = p0 >> 7, x0 = p0 & 127;
  const unsigned short* ip = in + ((size_t)b * Ctot + ch) * HW;
  const float* wp = wgt + ch * 9;
  float acc[8] = {};
  #pragma unroll
  for (int dy = -1; dy <= 1; ++dy) {
    int yy = y + dy;
    if (yy < 0 || yy > IMGW - 1) continue;
    const unsigned short* rp = ip + yy * IMGW;
    float r[10];
    bf16x8 mid = *(const bf16x8*)&rp[x0];
    #pragma unroll
    for (int e = 0; e < 8; ++e) r[e + 1] = bf2f(mid[e]);
    r[0] = (x0 > 0) ? bf2f(rp[x0 - 1]) : 0.f;
    r[9] = (x0 < 120) ? bf2f(rp[x0 + 8]) : 0.f;
    #pragma unroll
    for (int dx = 0; dx < 3; ++dx) {
      float wv = wp[(dy + 1) * 3 + dx];
      #pragma unroll
      for (int e = 0; e < 8; ++e) acc[e] += wv * r[e + dx];
    }
  }
  bf16x8 u;
  #pragma unroll
  for (int e = 0; e < 8; ++e) u[e] = f2bf(acc[e]);
  *(bf16x8*)&out[((size_t)b * Ctot + ch) * HW + p0] = u;
}

// ---------------------------------------------------------------------------
// L2 norms for Q, K2, K in one launch. inv[kind*384 + b*192 + r].
// ---------------------------------------------------------------------------
__global__ __launch_bounds__(256) void norm3_kernel(
    const unsigned short* __restrict__ qkvb,
    const unsigned short* __restrict__ kvb, float* __restrict__ inv) {
  const int kind = blockIdx.x / 384;
  const int row = blockIdx.x % 384;
  const int b = row / Cc, r = row % Cc;
  const unsigned short* p;
  if (kind == 0)      p = qkvb + (size_t)b * 3 * CP + (size_t)r * HW;
  else if (kind == 1) p = kvb + (size_t)b * 2 * CP + (size_t)r * HW;
  else                p = qkvb + (size_t)b * 3 * CP + CP + (size_t)r * HW;
  float s = 0.f;
  for (int i = threadIdx.x * 8; i < HW; i += 2048) {
    bf16x8 u = *(const bf16x8*)&p[i];
    #pragma unroll
    for (int j = 0; j < 8; ++j) {
      float v = bf2f(u[j]);
      s += v * v;
    }
  }
  #pragma unroll
  for (int off = 32; off; off >>= 1) s += __shfl_down(s, off);
  __shared__ float red[4];
  if ((threadIdx.x & 63) == 0) red[threadIdx.x >> 6] = s;
  __syncthreads();
  if (threadIdx.x == 0) {
    float t = red[0] + red[1] + red[2] + red[3];
    inv[blockIdx.x] = 1.f / fmaxf(sqrtf(t), 1e-12f);
  }
}

// ---------------------------------------------------------------------------
// Gram partials via MFMA, 3 pairs in one launch (blockIdx.z = pair).
// grid (16 chunks, 8 bh, 3); chunk = 1024 n -> 8 iters of 128.
// ---------------------------------------------------------------------------
#define PK 136
#define NCHUNK 16
__global__ __launch_bounds__(256) void gram_mfma_kernel(
    const unsigned short* __restrict__ qkvb,
    const unsigned short* __restrict__ kvb, float* __restrict__ spart) {
  __shared__ __align__(16) char lds_raw[4 * 2304 * 4];
  short* Qs = (short*)lds_raw;
  short* Ks = Qs + 48 * PK;
  float* Rs = (float*)lds_raw;
  const int pair = blockIdx.z;
  const int bh = blockIdx.y, b = bh >> 2, hd = bh & 3;
  const int n0 = blockIdx.x * 1024;
  const int tid = threadIdx.x, lane = tid & 63, wid = tid >> 6;
  const unsigned short *ap, *bp;
  size_t as_, bs_;
  if (pair == 0)      { ap = qkvb;      as_ = 3 * CP; bp = kvb;       bs_ = 2 * CP; }
  else if (pair == 1) { ap = kvb + CP;  as_ = 2 * CP; bp = qkvb + CP; bs_ = 3 * CP; }
  else                { ap = kvb + CP;  as_ = 2 * CP; bp = kvb + CP;  bs_ = 2 * CP; }
  const unsigned short* qb = ap + (size_t)b * as_ + (size_t)(hd * CH) * HW + n0;
  const unsigned short* kb = bp + (size_t)b * bs_ + (size_t)(hd * CH) * HW + n0;
  f32x4 acc[3][3] = {};
  #pragma unroll 1
  for (int it = 0; it < 8; ++it) {
    #pragma unroll
    for (int p = 0; p < 3; ++p) {
      int c = tid + p * 256;
      int row = c >> 4, col = c & 15;
      *(short8*)&Qs[row * PK + col * 8] =
          *(const short8*)(qb + (size_t)row * HW + it * 128 + col * 8);
      *(short8*)&Ks[row * PK + col * 8] =
          *(const short8*)(kb + (size_t)row * HW + it * 128 + col * 8);
    }
    __syncthreads();
    short8 af[3], bfr[3];
    #pragma unroll
    for (int t = 0; t < 3; ++t) {
      af[t]  = *(short8*)&Qs[(t * 16 + (lane & 15)) * PK + wid * 32 + (lane >> 4) * 8];
      bfr[t] = *(short8*)&Ks[(t * 16 + (lane & 15)) * PK + wid * 32 + (lane >> 4) * 8];
    }
    #pragma unroll
    for (int mt = 0; mt < 3; ++mt)
      #pragma unroll
      for (int nt = 0; nt < 3; ++nt)
        acc[mt][nt] = __builtin_amdgcn_mfma_f32_16x16x32_bf16(
            af[mt], bfr[nt], acc[mt][nt], 0, 0, 0);
    __syncthreads();
  }
  #pragma unroll
  for (int mt = 0; mt < 3; ++mt)
    #pragma unroll
    for (int nt = 0; nt < 3; ++nt)
      #pragma unroll
      for (int r = 0; r < 4; ++r) {
        int i = mt * 16 + ((lane >> 4) << 2) + r;
        int j = nt * 16 + (lane & 15);
        Rs[wid * 2304 + i * 48 + j] = acc[mt][nt][r];
      }
  __syncthreads();
  float* sp = spart + ((size_t)(pair * 8 + bh) * NCHUNK + blockIdx.x) * 2304;
  for (int e = tid; e < 2304; e += 256)
    sp[e] = Rs[e] + Rs[2304 + e] + Rs[2 * 2304 + e] + Rs[3 * 2304 + e];
}

// ---------------------------------------------------------------------------
// Reduce chunk-partials: G[(pair*8+bh)*2304 + e]
// ---------------------------------------------------------------------------
__global__ __launch_bounds__(256) void gram_reduce_kernel(
    const float* __restrict__ spart, float* __restrict__ G) {
  int idx = blockIdx.x * 256 + threadIdx.x;
  if (idx >= 3 * 8 * 2304) return;
  int pb = idx / 2304;
  int e = idx - pb * 2304;
  const float* sp = spart + (size_t)pb * NCHUNK * 2304 + e;
  float s = 0.f;
  #pragma unroll
  for (int c = 0; c < NCHUNK; ++c) s += sp[(size_t)c * 2304];
  G[idx] = s;
}

// ---------------------------------------------------------------------------
// Per-bh finalize -> A2 (global). One block per bh, register-tiled matmuls
// (16x16 threads, 3x3 outputs each) + 4-lane-group parallel softmax.
// G: pair0=Q*K2^T, pair1=V2*K^T, pair2=V2*V2^T.
// ---------------------------------------------------------------------------
__global__ __launch_bounds__(256) void finalize_a2_kernel(
    const float* __restrict__ G, const float* __restrict__ inv,
    const float* __restrict__ temp, float* __restrict__ attn2) {
  __shared__ float A1[2304], GVV[2304], GVK[2304], S2[2304];
  __shared__ float invq1[48];
  const int bh = blockIdx.x, b = bh >> 2, hd = bh & 3;
  const int tid = threadIdx.x;
  const float tp = temp[hd];
  const float* invQ  = inv;
  const float* invK2 = inv + 384;
  const float* invK  = inv + 768;
  // stage: scaled S1 -> A1; Gvv, Gvk
  for (int e = tid; e < 2304; e += 256) {
    int i = e / 48, j = e - i * 48;
    A1[e] = G[(size_t)(0 * 8 + bh) * 2304 + e] *
            invQ[b * Cc + hd * CH + i] * invK2[b * Cc + hd * CH + j] * tp;
    GVV[e] = G[(size_t)(2 * 8 + bh) * 2304 + e];
    GVK[e] = G[(size_t)(1 * 8 + bh) * 2304 + e];
  }
  __syncthreads();
  // softmax rows of A1 (4 lanes per row, 12 j each)
  if (tid < 192) {
    const int i = tid >> 2, g = tid & 3;
    float v[12];
    float m = -1e30f;
    #pragma unroll
    for (int k = 0; k < 12; ++k) {
      v[k] = A1[i * 48 + g * 12 + k];
      m = fmaxf(m, v[k]);
    }
    m = fmaxf(m, __shfl_xor(m, 1));
    m = fmaxf(m, __shfl_xor(m, 2));
    float sum = 0.f;
    #pragma unroll
    for (int k = 0; k < 12; ++k) {
      v[k] = expf(v[k] - m);
      sum += v[k];
    }
    sum += __shfl_xor(sum, 1);
    sum += __shfl_xor(sum, 2);
    float r = 1.f / sum;
    #pragma unroll
    for (int k = 0; k < 12; ++k) A1[i * 48 + g * 12 + k] = v[k] * r;
  }
  __syncthreads();
  // C = A1 * GVV (3x3 per thread), then invq1 via row-dot with A1
  const int ti = tid >> 4, tj = tid & 15;
  {
    float c[3][3] = {};
    #pragma unroll 4
    for (int d = 0; d < 48; ++d) {
      float a0 = A1[ti * 48 + d], a1 = A1[(ti + 16) * 48 + d],
            a2 = A1[(ti + 32) * 48 + d];
      float b0 = GVV[d * 48 + tj], b1 = GVV[d * 48 + tj + 16],
            b2 = GVV[d * 48 + tj + 32];
      c[0][0] += a0 * b0; c[0][1] += a0 * b1; c[0][2] += a0 * b2;
      c[1][0] += a1 * b0; c[1][1] += a1 * b1; c[1][2] += a1 * b2;
      c[2][0] += a2 * b0; c[2][1] += a2 * b1; c[2][2] += a2 * b2;
    }
    #pragma unroll
    for (int ii = 0; ii < 3; ++ii) {
      float p = 0.f;
      #pragma unroll
      for (int jj = 0; jj < 3; ++jj)
        p += c[ii][jj] * A1[(ti + 16 * ii) * 48 + tj + 16 * jj];
      p += __shfl_xor(p, 1);
      p += __shfl_xor(p, 2);
      p += __shfl_xor(p, 4);
      p += __shfl_xor(p, 8);
      if (tj == 0)
        invq1[ti + 16 * ii] = 1.f / fmaxf(sqrtf(fmaxf(p, 0.f)), 1e-12f);
    }
  }
  __syncthreads();
  // S2 = diag(invq1) * (A1*GVK) * diag(invK) * tp
  {
    float s[3][3] = {};
    #pragma unroll 4
    for (int d = 0; d < 48; ++d) {
      float a0 = A1[ti * 48 + d], a1 = A1[(ti + 16) * 48 + d],
            a2 = A1[(ti + 32) * 48 + d];
      float b0 = GVK[d * 48 + tj], b1 = GVK[d * 48 + tj + 16],
            b2 = GVK[d * 48 + tj + 32];
      s[0][0] += a0 * b0; s[0][1] += a0 * b1; s[0][2] += a0 * b2;
      s[1][0] += a1 * b0; s[1][1] += a1 * b1; s[1][2] += a1 * b2;
      s[2][0] += a2 * b0; s[2][1] += a2 * b1; s[2][2] += a2 * b2;
    }
    #pragma unroll
    for (int ii = 0; ii < 3; ++ii)
      #pragma unroll
      for (int jj = 0; jj < 3; ++jj) {
        int i = ti + 16 * ii, j = tj + 16 * jj;
        S2[i * 48 + j] = s[ii][jj] * invq1[i] *
                         invK[b * Cc + hd * CH + j] * tp;
      }
  }
  __syncthreads();
  // softmax rows of S2 -> attn2 (global)
  if (tid < 192) {
    const int i = tid >> 2, g = tid & 3;
    float v[12];
    float m = -1e30f;
    #pragma unroll
    for (int k = 0; k < 12; ++k) {
      v[k] = S2[i * 48 + g * 12 + k];
      m = fmaxf(m, v[k]);
    }
    m = fmaxf(m, __shfl_xor(m, 1));
    m = fmaxf(m, __shfl_xor(m, 2));
    float sum = 0.f;
    #pragma unroll
    for (int k = 0; k < 12; ++k) {
      v[k] = expf(v[k] - m);
      sum += v[k];
    }
    sum += __shfl_xor(sum, 1);
    sum += __shfl_xor(sum, 2);
    float r = 1.f / sum;
    #pragma unroll
    for (int k = 0; k < 12; ++k)
      attn2[(size_t)bh * 2304 + i * 48 + g * 12 + k] = v[k] * r;
  }
}

// ---------------------------------------------------------------------------
// M[b][o][c] = sum_i P[o][hd*48+i] * A2[b][hd][i][c%48],  hd = c/48 (bf16 out)
// ---------------------------------------------------------------------------
__global__ __launch_bounds__(192) void mproj_kernel(
    const float* __restrict__ P, const float* __restrict__ attn2,
    unsigned short* __restrict__ Mb) {
  const int b = blockIdx.y, o = blockIdx.x;
  const int c = threadIdx.x;
  const int hd = c / 48, j = c - hd * 48;
  const float* prow = P + (size_t)o * Cc + hd * 48;
  const float* arow = attn2 + (size_t)(b * 4 + hd) * 2304 + j;
  float s = 0.f;
  #pragma unroll 8
  for (int i = 0; i < 48; ++i) s += prow[i] * arow[(size_t)i * 48];
  Mb[((size_t)b * Cc + o) * Cc + c] = f2bf(s);
}

// ---------------------------------------------------------------------------
// Transpose bf16 [c][hw] (stride vbs per batch) -> [b][hw][192].
// ---------------------------------------------------------------------------
__global__ __launch_bounds__(256) void vtrans_kernel(
    const unsigned short* __restrict__ v, size_t vbs,
    unsigned short* __restrict__ vt) {
  __shared__ unsigned short LT[64 * 65];
  const int b = blockIdx.z;
  const int c0 = blockIdx.y * 64;
  const int h0 = blockIdx.x * 64;
  const int tid = threadIdx.x;
  const unsigned short* ip = v + (size_t)b * vbs + (size_t)c0 * HW + h0;
  #pragma unroll
  for (int e = 0; e < 2; ++e) {
    int idx = e * 256 + tid;             // 0..511
    int c = idx >> 3, hg = idx & 7;
    bf16x8 r = *(const bf16x8*)(ip + (size_t)c * HW + hg * 8);
    #pragma unroll
    for (int j = 0; j < 8; ++j) LT[c * 65 + hg * 8 + j] = r[j];
  }
  __syncthreads();
  unsigned short* op = vt + (size_t)b * CP + (size_t)h0 * Cc + c0;
  #pragma unroll
  for (int e = 0; e < 2; ++e) {
    int idx = e * 256 + tid;
    int hw = idx >> 3, cg = idx & 7;
    bf16x8 u;
    #pragma unroll
    for (int j = 0; j < 8; ++j) u[j] = LT[(cg * 8 + j) * 65 + hw];
    *(bf16x8*)&op[(size_t)hw * Cc + cg * 8] = u;
  }
}

// ---------------------------------------------------------------------------
extern "C" void kernel_launch(void* const* d_in, const int* in_sizes, int n_in,
                              void* d_out, int out_size, void* d_ws, size_t ws_size,
                              hipStream_t stream) {
  const float* x      = (const float*)d_in[0];
  const float* y      = (const float*)d_in[1];
  const float* qkv_w  = (const float*)d_in[2];
  const float* dw_w   = (const float*)d_in[3];
  const float* kv_w   = (const float*)d_in[4];
  const float* proj_w = (const float*)d_in[5];
  const float* temp   = (const float*)d_in[6];
  float* out = (float*)d_out;
  float* ws  = (float*)d_ws;

  const size_t SF = (size_t)Bsz * CP;   // 6,291,456 elements
  unsigned short* qkvb   = (unsigned short*)ws;                 // 3SF shorts
  unsigned short* kvb    = (unsigned short*)(ws + 3 * SF / 2);  // 2SF shorts
  unsigned short* qkvpre = (unsigned short*)(ws + 5 * SF / 2);  // 3SF shorts -> 4SF
  unsigned short* xt     = (unsigned short*)(ws + 4 * SF);      // SF shorts
  unsigned short* vt     = xt;                                  // reuse after conv qkv
  unsigned short* yt     = (unsigned short*)(ws + 9 * SF / 2);  // SF shorts -> 5SF
  float* inv   = ws + 5 * SF;                           // 1152
  float* spart = inv + 1152;                            // 3*8*16*2304
  float* G     = spart + (size_t)3 * 8 * NCHUNK * 2304; // 55,296
  float* attn2 = G + 3 * 8 * 2304;                      // 18,432
  unsigned short* Mb   = (unsigned short*)(attn2 + 8 * 2304);
  unsigned short* wqkv = Mb + (size_t)Bsz * Cc * Cc;
  unsigned short* wkv  = wqkv + NWQKV;

  dim3 blk(256);

  // 0. casts (weights; x+y transposed)
  cast_weights_kernel<<<dim3((NWQKV + NWKV + 255) / 256), blk, 0, stream>>>(
      qkv_w, kv_w, wqkv, wkv);
  cast_xy_kernel<<<dim3(HW / 256, Cc / 8, 2 * Bsz), blk, 0, stream>>>(
      x, y, xt, yt);

  // 1. qkv_pre = conv1x1(x, qkv_w) -> bf16 [c][hw]
  conv_mfma_kernel<1><<<dim3(HW / BMH, 576 / BNO, Bsz), blk, 0, stream>>>(
      xt, wqkv, qkvpre, 3 * Cc, 0);
  // 2. qkv = dwconv3x3(qkv_pre)
  dwconv_kernel<<<dim3(HW / 2048, 3 * Cc, Bsz), blk, 0, stream>>>(
      qkvpre, dw_w, qkvb, 3 * Cc);
  // 3. kv = conv1x1(y, kv_w)
  conv_mfma_kernel<1><<<dim3(HW / BMH, 384 / BNO, Bsz), blk, 0, stream>>>(
      yt, wkv, kvb, 2 * Cc, 0);

  // 4. norms (Q, K2, K)
  norm3_kernel<<<dim3(3 * 384), blk, 0, stream>>>(qkvb, kvb, inv);

  // 5. Gram partials (3 pairs) + reduce
  gram_mfma_kernel<<<dim3(NCHUNK, 8, 3), blk, 0, stream>>>(qkvb, kvb, spart);
  gram_reduce_kernel<<<dim3(216), blk, 0, stream>>>(spart, G);

  // 6. finalize -> A2; M = P * A2_blockdiag
  finalize_a2_kernel<<<dim3(8), blk, 0, stream>>>(G, inv, temp, attn2);
  mproj_kernel<<<dim3(Cc, Bsz), dim3(192), 0, stream>>>(proj_w, attn2, Mb);

  // 7. out = M * V (V transposed to [hw][c] first)
  vtrans_kernel<<<dim3(HW / 64, Cc / 64, Bsz), blk, 0, stream>>>(
      qkvb + 2 * CP, 3 * CP, vt);
  conv_mfma_kernel<0><<<dim3(HW / BMH, Cc / BNO, Bsz), blk, 0, stream>>>(
      vt, Mb, out, Cc, (size_t)Cc * Cc);
}

// Round 9
// 117.243 us; speedup vs baseline: 1.5836x; 1.1280x over previous
//
#include <hip/hip_runtime.h>
#include <hip/hip_bf16.h>

// Problem constants
#define HW 16384        // 128*128
#define IMGW 128
#define Bsz 2
#define Cc 192          // channels
#define NH 4
#define CH 48
static const size_t CP = (size_t)Cc * HW;   // one batch's 192-channel block

typedef __attribute__((ext_vector_type(4))) float f32x4;
typedef __attribute__((ext_vector_type(8))) short short8;
typedef __attribute__((ext_vector_type(8))) unsigned short bf16x8;
typedef __attribute__((ext_vector_type(4))) unsigned short bf16x4;

__device__ __forceinline__ unsigned short f2bf(float f) {
  __hip_bfloat16 h = __float2bfloat16(f);
  return *reinterpret_cast<unsigned short*>(&h);
}
__device__ __forceinline__ float bf2f(unsigned short u) {
  union { unsigned int i; float f; } v;
  v.i = (unsigned int)u << 16;
  return v.f;
}

// ---------------------------------------------------------------------------
// weights fp32 -> bf16 (both weight mats, one launch)
// ---------------------------------------------------------------------------
#define NWQKV (576 * 192)
#define NWKV  (384 * 192)
__global__ __launch_bounds__(256) void cast_weights_kernel(
    const float* __restrict__ qkv_w, const float* __restrict__ kv_w,
    unsigned short* __restrict__ wqkv, unsigned short* __restrict__ wkv) {
  int i = blockIdx.x * 256 + threadIdx.x;
  if (i < NWQKV) wqkv[i] = f2bf(qkv_w[i]);
  else if (i < NWQKV + NWKV) wkv[i - NWQKV] = f2bf(kv_w[i - NWQKV]);
}

// ---------------------------------------------------------------------------
// conv1x1 bf16 MFMA GEMM, stage-A-once + inner o-loop.
// D[m=hw][n=o] = sum_c SRC[c][hw] * W[o][c]
// INKIND 1: src fp32 [c][hw] (cast fused); INKIND 2: src bf16 [c][hw].
// Transpose staged in LDS with COALESCED reads: lanes walk hw within a row
// (16 lanes x f32x4/bf16x4), (c,c+1) packed to u32 -> As32[hw][c/2].
// Tile 64(hw) x 64(o) per o-step, full K=192 resident. 4 waves (2m x 2n).
// ---------------------------------------------------------------------------
#define APAD 200   // shorts per LDS row (192 + 8); 400B stride; %16B==0

template <int INKIND, int OUTBF16>
__global__ __launch_bounds__(256) void conv_mfma_kernel(
    const void* __restrict__ src, size_t src_bstride,      // elements
    const unsigned short* __restrict__ wb, size_t wstride, // per-batch (0=shared)
    void* __restrict__ outv, int Cout) {
  __shared__ __align__(16) short As[64 * APAD];
  __shared__ __align__(16) short Bs[64 * APAD];
  unsigned int* As32 = (unsigned int*)As;
  const int b = blockIdx.z;
  const int hw0 = blockIdx.x * 64;
  const int tid = threadIdx.x;
  const int lane = tid & 63, wid = tid >> 6;
  const int wm = wid & 1, wn = wid >> 1;
  const int l = tid & 15, pp0 = tid >> 4;    // staging coords
  const unsigned short* wbbase = wb + (size_t)b * wstride;
  const int NT = Cout >> 6;

  // ---- stage A once: all 192 c, fused transpose ----
  #pragma unroll
  for (int kp = 0; kp < 3; ++kp) {
    #pragma unroll
    for (int it = 0; it < 2; ++it) {
      int pp = pp0 + 16 * it;                // c-pair within k-slice, 0..31
      int c0 = kp * 64 + 2 * pp;
      if (INKIND == 1) {
        const float* r0 = (const float*)src + (size_t)b * src_bstride +
                          (size_t)c0 * HW + hw0 + l * 4;
        f32x4 v0 = *(const f32x4*)r0;
        f32x4 v1 = *(const f32x4*)(r0 + HW);
        #pragma unroll
        for (int i = 0; i < 4; ++i)
          As32[(l * 4 + i) * (APAD / 2) + kp * 32 + pp] =
              (unsigned int)f2bf(v0[i]) | ((unsigned int)f2bf(v1[i]) << 16);
      } else {
        const unsigned short* r0 = (const unsigned short*)src +
                                   (size_t)b * src_bstride +
                                   (size_t)c0 * HW + hw0 + l * 4;
        bf16x4 v0 = *(const bf16x4*)r0;
        bf16x4 v1 = *(const bf16x4*)(r0 + HW);
        #pragma unroll
        for (int i = 0; i < 4; ++i)
          As32[(l * 4 + i) * (APAD / 2) + kp * 32 + pp] =
              (unsigned int)v0[i] | ((unsigned int)v1[i] << 16);
      }
    }
  }

  for (int ot = 0; ot < NT; ++ot) {
    const unsigned short* wbb = wbbase + (size_t)(ot * 64) * Cc;
    // ---- stage B for this o-tile: 64 rows x 192 c ----
    #pragma unroll
    for (int p = 0; p < 6; ++p) {
      int i = tid + p * 256;                 // 0..1535
      int row = i / 24, cc = i - (i / 24) * 24;
      *(short8*)&Bs[row * APAD + cc * 8] =
          *(const short8*)(wbb + (size_t)row * Cc + cc * 8);
    }
    __syncthreads();                         // A (first ot) + B ready
    f32x4 acc[2][2] = {};
    #pragma unroll
    for (int ks = 0; ks < 6; ++ks) {
      short8 bfrag[2];
      #pragma unroll
      for (int fn = 0; fn < 2; ++fn)
        bfrag[fn] = *(short8*)&Bs[(wn * 32 + fn * 16 + (lane & 15)) * APAD +
                                  ks * 32 + (lane >> 4) * 8];
      #pragma unroll
      for (int fm = 0; fm < 2; ++fm) {
        short8 afrag = *(short8*)&As[(wm * 32 + fm * 16 + (lane & 15)) * APAD +
                                     ks * 32 + (lane >> 4) * 8];
        #pragma unroll
        for (int fn = 0; fn < 2; ++fn)
          acc[fm][fn] = __builtin_amdgcn_mfma_f32_16x16x32_bf16(
              afrag, bfrag[fn], acc[fm][fn], 0, 0, 0);
      }
    }
    __syncthreads();                         // done reading Bs before next ot
    // ---- epilogue for this o-tile (registers only) ----
    #pragma unroll
    for (int fm = 0; fm < 2; ++fm)
      #pragma unroll
      for (int fn = 0; fn < 2; ++fn) {
        int o = ot * 64 + wn * 32 + fn * 16 + (lane & 15);
        int hw = hw0 + wm * 32 + fm * 16 + ((lane >> 4) << 2);
        if (OUTBF16) {
          bf16x4 u;
          #pragma unroll
          for (int r = 0; r < 4; ++r) u[r] = f2bf(acc[fm][fn][r]);
          *(bf16x4*)&((unsigned short*)outv)[((size_t)b * Cout + o) * HW + hw] = u;
        } else {
          *(f32x4*)&((float*)outv)[((size_t)b * Cout + o) * HW + hw] = acc[fm][fn];
        }
      }
  }
}

// ---------------------------------------------------------------------------
// depthwise 3x3 SAME, bf16 in/out, fp32 accum. 8 px/thread.
// ---------------------------------------------------------------------------
__global__ __launch_bounds__(256) void dwconv_kernel(
    const unsigned short* __restrict__ in, const float* __restrict__ wgt,
    unsigned short* __restrict__ out, int Ctot) {
  const int b = blockIdx.z, ch = blockIdx.y;
  const int p0 = blockIdx.x * 2048 + threadIdx.x * 8;
  const int y = p0 >> 7, x0 = p0 & 127;
  const unsigned short* ip = in + ((size_t)b * Ctot + ch) * HW;
  const float* wp = wgt + ch * 9;
  float acc[8] = {};
  #pragma unroll
  for (int dy = -1; dy <= 1; ++dy) {
    int yy = y + dy;
    if (yy < 0 || yy > IMGW - 1) continue;
    const unsigned short* rp = ip + yy * IMGW;
    float r[10];
    bf16x8 mid = *(const bf16x8*)&rp[x0];
    #pragma unroll
    for (int e = 0; e < 8; ++e) r[e + 1] = bf2f(mid[e]);
    r[0] = (x0 > 0) ? bf2f(rp[x0 - 1]) : 0.f;
    r[9] = (x0 < 120) ? bf2f(rp[x0 + 8]) : 0.f;
    #pragma unroll
    for (int dx = 0; dx < 3; ++dx) {
      float wv = wp[(dy + 1) * 3 + dx];
      #pragma unroll
      for (int e = 0; e < 8; ++e) acc[e] += wv * r[e + dx];
    }
  }
  bf16x8 u;
  #pragma unroll
  for (int e = 0; e < 8; ++e) u[e] = f2bf(acc[e]);
  *(bf16x8*)&out[((size_t)b * Ctot + ch) * HW + p0] = u;
}

// ---------------------------------------------------------------------------
// L2 norms for Q, K2, K in one launch. inv[kind*384 + b*192 + r].
// ---------------------------------------------------------------------------
__global__ __launch_bounds__(256) void norm3_kernel(
    const unsigned short* __restrict__ qkvb,
    const unsigned short* __restrict__ kvb, float* __restrict__ inv) {
  const int kind = blockIdx.x / 384;
  const int row = blockIdx.x % 384;
  const int b = row / Cc, r = row % Cc;
  const unsigned short* p;
  if (kind == 0)      p = qkvb + (size_t)b * 3 * CP + (size_t)r * HW;
  else if (kind == 1) p = kvb + (size_t)b * 2 * CP + (size_t)r * HW;
  else                p = qkvb + (size_t)b * 3 * CP + CP + (size_t)r * HW;
  float s = 0.f;
  for (int i = threadIdx.x * 8; i < HW; i += 2048) {
    bf16x8 u = *(const bf16x8*)&p[i];
    #pragma unroll
    for (int j = 0; j < 8; ++j) {
      float v = bf2f(u[j]);
      s += v * v;
    }
  }
  #pragma unroll
  for (int off = 32; off; off >>= 1) s += __shfl_down(s, off);
  __shared__ float red[4];
  if ((threadIdx.x & 63) == 0) red[threadIdx.x >> 6] = s;
  __syncthreads();
  if (threadIdx.x == 0) {
    float t = red[0] + red[1] + red[2] + red[3];
    inv[blockIdx.x] = 1.f / fmaxf(sqrtf(t), 1e-12f);
  }
}

// ---------------------------------------------------------------------------
// Gram partials via MFMA, 3 pairs in one launch (blockIdx.z = pair).
// grid (16 chunks, 8 bh, 3); chunk = 1024 n -> 8 iters of 128.
// ---------------------------------------------------------------------------
#define PK 136
#define NCHUNK 16
__global__ __launch_bounds__(256) void gram_mfma_kernel(
    const unsigned short* __restrict__ qkvb,
    const unsigned short* __restrict__ kvb, float* __restrict__ spart) {
  __shared__ __align__(16) char lds_raw[4 * 2304 * 4];
  short* Qs = (short*)lds_raw;
  short* Ks = Qs + 48 * PK;
  float* Rs = (float*)lds_raw;
  const int pair = blockIdx.z;
  const int bh = blockIdx.y, b = bh >> 2, hd = bh & 3;
  const int n0 = blockIdx.x * 1024;
  const int tid = threadIdx.x, lane = tid & 63, wid = tid >> 6;
  const unsigned short *ap, *bp;
  size_t as_, bs_;
  if (pair == 0)      { ap = qkvb;      as_ = 3 * CP; bp = kvb;       bs_ = 2 * CP; }
  else if (pair == 1) { ap = kvb + CP;  as_ = 2 * CP; bp = qkvb + CP; bs_ = 3 * CP; }
  else                { ap = kvb + CP;  as_ = 2 * CP; bp = kvb + CP;  bs_ = 2 * CP; }
  const unsigned short* qb = ap + (size_t)b * as_ + (size_t)(hd * CH) * HW + n0;
  const unsigned short* kb = bp + (size_t)b * bs_ + (size_t)(hd * CH) * HW + n0;
  f32x4 acc[3][3] = {};
  #pragma unroll 1
  for (int it = 0; it < 8; ++it) {
    #pragma unroll
    for (int p = 0; p < 3; ++p) {
      int c = tid + p * 256;
      int row = c >> 4, col = c & 15;
      *(short8*)&Qs[row * PK + col * 8] =
          *(const short8*)(qb + (size_t)row * HW + it * 128 + col * 8);
      *(short8*)&Ks[row * PK + col * 8] =
          *(const short8*)(kb + (size_t)row * HW + it * 128 + col * 8);
    }
    __syncthreads();
    short8 af[3], bfr[3];
    #pragma unroll
    for (int t = 0; t < 3; ++t) {
      af[t]  = *(short8*)&Qs[(t * 16 + (lane & 15)) * PK + wid * 32 + (lane >> 4) * 8];
      bfr[t] = *(short8*)&Ks[(t * 16 + (lane & 15)) * PK + wid * 32 + (lane >> 4) * 8];
    }
    #pragma unroll
    for (int mt = 0; mt < 3; ++mt)
      #pragma unroll
      for (int nt = 0; nt < 3; ++nt)
        acc[mt][nt] = __builtin_amdgcn_mfma_f32_16x16x32_bf16(
            af[mt], bfr[nt], acc[mt][nt], 0, 0, 0);
    __syncthreads();
  }
  #pragma unroll
  for (int mt = 0; mt < 3; ++mt)
    #pragma unroll
    for (int nt = 0; nt < 3; ++nt)
      #pragma unroll
      for (int r = 0; r < 4; ++r) {
        int i = mt * 16 + ((lane >> 4) << 2) + r;
        int j = nt * 16 + (lane & 15);
        Rs[wid * 2304 + i * 48 + j] = acc[mt][nt][r];
      }
  __syncthreads();
  float* sp = spart + ((size_t)(pair * 8 + bh) * NCHUNK + blockIdx.x) * 2304;
  for (int e = tid; e < 2304; e += 256)
    sp[e] = Rs[e] + Rs[2304 + e] + Rs[2 * 2304 + e] + Rs[3 * 2304 + e];
}

// ---------------------------------------------------------------------------
// Reduce chunk-partials: G[(pair*8+bh)*2304 + e]
// ---------------------------------------------------------------------------
__global__ __launch_bounds__(256) void gram_reduce_kernel(
    const float* __restrict__ spart, float* __restrict__ G) {
  int idx = blockIdx.x * 256 + threadIdx.x;
  if (idx >= 3 * 8 * 2304) return;
  int pb = idx / 2304;
  int e = idx - pb * 2304;
  const float* sp = spart + (size_t)pb * NCHUNK * 2304 + e;
  float s = 0.f;
  #pragma unroll
  for (int c = 0; c < NCHUNK; ++c) s += sp[(size_t)c * 2304];
  G[idx] = s;
}

// ---------------------------------------------------------------------------
// Per-bh finalize -> A2 (global). Register-tiled matmuls + 4-lane softmax.
// G: pair0=Q*K2^T, pair1=V2*K^T, pair2=V2*V2^T.
// ---------------------------------------------------------------------------
__global__ __launch_bounds__(256) void finalize_a2_kernel(
    const float* __restrict__ G, const float* __restrict__ inv,
    const float* __restrict__ temp, float* __restrict__ attn2) {
  __shared__ float A1[2304], GVV[2304], GVK[2304], S2[2304];
  __shared__ float invq1[48];
  const int bh = blockIdx.x, b = bh >> 2, hd = bh & 3;
  const int tid = threadIdx.x;
  const float tp = temp[hd];
  const float* invQ  = inv;
  const float* invK2 = inv + 384;
  const float* invK  = inv + 768;
  for (int e = tid; e < 2304; e += 256) {
    int i = e / 48, j = e - i * 48;
    A1[e] = G[(size_t)(0 * 8 + bh) * 2304 + e] *
            invQ[b * Cc + hd * CH + i] * invK2[b * Cc + hd * CH + j] * tp;
    GVV[e] = G[(size_t)(2 * 8 + bh) * 2304 + e];
    GVK[e] = G[(size_t)(1 * 8 + bh) * 2304 + e];
  }
  __syncthreads();
  if (tid < 192) {
    const int i = tid >> 2, g = tid & 3;
    float v[12];
    float m = -1e30f;
    #pragma unroll
    for (int k = 0; k < 12; ++k) {
      v[k] = A1[i * 48 + g * 12 + k];
      m = fmaxf(m, v[k]);
    }
    m = fmaxf(m, __shfl_xor(m, 1));
    m = fmaxf(m, __shfl_xor(m, 2));
    float sum = 0.f;
    #pragma unroll
    for (int k = 0; k < 12; ++k) {
      v[k] = expf(v[k] - m);
      sum += v[k];
    }
    sum += __shfl_xor(sum, 1);
    sum += __shfl_xor(sum, 2);
    float r = 1.f / sum;
    #pragma unroll
    for (int k = 0; k < 12; ++k) A1[i * 48 + g * 12 + k] = v[k] * r;
  }
  __syncthreads();
  const int ti = tid >> 4, tj = tid & 15;
  {
    float c[3][3] = {};
    #pragma unroll 4
    for (int d = 0; d < 48; ++d) {
      float a0 = A1[ti * 48 + d], a1 = A1[(ti + 16) * 48 + d],
            a2 = A1[(ti + 32) * 48 + d];
      float b0 = GVV[d * 48 + tj], b1 = GVV[d * 48 + tj + 16],
            b2 = GVV[d * 48 + tj + 32];
      c[0][0] += a0 * b0; c[0][1] += a0 * b1; c[0][2] += a0 * b2;
      c[1][0] += a1 * b0; c[1][1] += a1 * b1; c[1][2] += a1 * b2;
      c[2][0] += a2 * b0; c[2][1] += a2 * b1; c[2][2] += a2 * b2;
    }
    #pragma unroll
    for (int ii = 0; ii < 3; ++ii) {
      float p = 0.f;
      #pragma unroll
      for (int jj = 0; jj < 3; ++jj)
        p += c[ii][jj] * A1[(ti + 16 * ii) * 48 + tj + 16 * jj];
      p += __shfl_xor(p, 1);
      p += __shfl_xor(p, 2);
      p += __shfl_xor(p, 4);
      p += __shfl_xor(p, 8);
      if (tj == 0)
        invq1[ti + 16 * ii] = 1.f / fmaxf(sqrtf(fmaxf(p, 0.f)), 1e-12f);
    }
  }
  __syncthreads();
  {
    float s[3][3] = {};
    #pragma unroll 4
    for (int d = 0; d < 48; ++d) {
      float a0 = A1[ti * 48 + d], a1 = A1[(ti + 16) * 48 + d],
            a2 = A1[(ti + 32) * 48 + d];
      float b0 = GVK[d * 48 + tj], b1 = GVK[d * 48 + tj + 16],
            b2 = GVK[d * 48 + tj + 32];
      s[0][0] += a0 * b0; s[0][1] += a0 * b1; s[0][2] += a0 * b2;
      s[1][0] += a1 * b0; s[1][1] += a1 * b1; s[1][2] += a1 * b2;
      s[2][0] += a2 * b0; s[2][1] += a2 * b1; s[2][2] += a2 * b2;
    }
    #pragma unroll
    for (int ii = 0; ii < 3; ++ii)
      #pragma unroll
      for (int jj = 0; jj < 3; ++jj) {
        int i = ti + 16 * ii, j = tj + 16 * jj;
        S2[i * 48 + j] = s[ii][jj] * invq1[i] *
                         invK[b * Cc + hd * CH + j] * tp;
      }
  }
  __syncthreads();
  if (tid < 192) {
    const int i = tid >> 2, g = tid & 3;
    float v[12];
    float m = -1e30f;
    #pragma unroll
    for (int k = 0; k < 12; ++k) {
      v[k] = S2[i * 48 + g * 12 + k];
      m = fmaxf(m, v[k]);
    }
    m = fmaxf(m, __shfl_xor(m, 1));
    m = fmaxf(m, __shfl_xor(m, 2));
    float sum = 0.f;
    #pragma unroll
    for (int k = 0; k < 12; ++k) {
      v[k] = expf(v[k] - m);
      sum += v[k];
    }
    sum += __shfl_xor(sum, 1);
    sum += __shfl_xor(sum, 2);
    float r = 1.f / sum;
    #pragma unroll
    for (int k = 0; k < 12; ++k)
      attn2[(size_t)bh * 2304 + i * 48 + g * 12 + k] = v[k] * r;
  }
}

// ---------------------------------------------------------------------------
// M[b][o][c] = sum_i P[o][hd*48+i] * A2[b][hd][i][c%48],  hd = c/48 (bf16 out)
// ---------------------------------------------------------------------------
__global__ __launch_bounds__(192) void mproj_kernel(
    const float* __restrict__ P, const float* __restrict__ attn2,
    unsigned short* __restrict__ Mb) {
  const int b = blockIdx.y, o = blockIdx.x;
  const int c = threadIdx.x;
  const int hd = c / 48, j = c - hd * 48;
  const float* prow = P + (size_t)o * Cc + hd * 48;
  const float* arow = attn2 + (size_t)(b * 4 + hd) * 2304 + j;
  float s = 0.f;
  #pragma unroll 8
  for (int i = 0; i < 48; ++i) s += prow[i] * arow[(size_t)i * 48];
  Mb[((size_t)b * Cc + o) * Cc + c] = f2bf(s);
}

// ---------------------------------------------------------------------------
extern "C" void kernel_launch(void* const* d_in, const int* in_sizes, int n_in,
                              void* d_out, int out_size, void* d_ws, size_t ws_size,
                              hipStream_t stream) {
  const float* x      = (const float*)d_in[0];
  const float* y      = (const float*)d_in[1];
  const float* qkv_w  = (const float*)d_in[2];
  const float* dw_w   = (const float*)d_in[3];
  const float* kv_w   = (const float*)d_in[4];
  const float* proj_w = (const float*)d_in[5];
  const float* temp   = (const float*)d_in[6];
  float* out = (float*)d_out;
  float* ws  = (float*)d_ws;

  const size_t SF = (size_t)Bsz * CP;   // 6,291,456 elements
  unsigned short* qkvb   = (unsigned short*)ws;                 // 3SF shorts
  unsigned short* kvb    = (unsigned short*)(ws + 3 * SF / 2);  // 2SF shorts
  unsigned short* qkvpre = (unsigned short*)(ws + 5 * SF / 2);  // 3SF shorts -> 4SF
  float* inv   = ws + 4 * SF;                           // 1152
  float* spart = inv + 1152;                            // 3*8*16*2304
  float* G     = spart + (size_t)3 * 8 * NCHUNK * 2304; // 55,296
  float* attn2 = G + 3 * 8 * 2304;                      // 18,432
  unsigned short* Mb   = (unsigned short*)(attn2 + 8 * 2304);
  unsigned short* wqkv = Mb + (size_t)Bsz * Cc * Cc;
  unsigned short* wkv  = wqkv + NWQKV;

  dim3 blk(256);

  // 0. weight casts
  cast_weights_kernel<<<dim3((NWQKV + NWKV + 255) / 256), blk, 0, stream>>>(
      qkv_w, kv_w, wqkv, wkv);

  // 1. qkv_pre = conv1x1(x, qkv_w)  [fp32 src, fused cast+transpose, A once]
  conv_mfma_kernel<1, 1><<<dim3(HW / 64, 1, Bsz), blk, 0, stream>>>(
      x, CP, wqkv, 0, qkvpre, 3 * Cc);
  // 2. qkv = dwconv3x3(qkv_pre)
  dwconv_kernel<<<dim3(HW / 2048, 3 * Cc, Bsz), blk, 0, stream>>>(
      qkvpre, dw_w, qkvb, 3 * Cc);
  // 3. kv = conv1x1(y, kv_w)
  conv_mfma_kernel<1, 1><<<dim3(HW / 64, 1, Bsz), blk, 0, stream>>>(
      y, CP, wkv, 0, kvb, 2 * Cc);

  // 4. norms (Q, K2, K)
  norm3_kernel<<<dim3(3 * 384), blk, 0, stream>>>(qkvb, kvb, inv);

  // 5. Gram partials (3 pairs) + reduce
  gram_mfma_kernel<<<dim3(NCHUNK, 8, 3), blk, 0, stream>>>(qkvb, kvb, spart);
  gram_reduce_kernel<<<dim3(216), blk, 0, stream>>>(spart, G);

  // 6. finalize -> A2; M = P * A2_blockdiag
  finalize_a2_kernel<<<dim3(8), blk, 0, stream>>>(G, inv, temp, attn2);
  mproj_kernel<<<dim3(Cc, Bsz), dim3(192), 0, stream>>>(proj_w, attn2, Mb);

  // 7. out = M * V  (V bf16 [c][hw] read directly, fused transpose)
  conv_mfma_kernel<2, 0><<<dim3(HW / 64, 1, Bsz), blk, 0, stream>>>(
      qkvb + 2 * CP, 3 * CP, Mb, (size_t)Cc * Cc, out, Cc);
}